// Round 1
// baseline (2059.638 us; speedup 1.0000x reference)
//
#include <hip/hip_runtime.h>
#include <hip/hip_bf16.h>
#include <math.h>

#define B 4
#define C 256
#define G 8
#define CPG 32
#define N 4096
#define OC 768
#define EPSV 1e-5f
#define SCALE 0.0625f   // 1/sqrt(256)

// ---------------- K1a: groupnorm partial sums ----------------
// grid 256: blk = bg*8 + part; each group's 32 channels are contiguous in x.
__global__ __launch_bounds__(256) void gn_partial(const float* __restrict__ x,
                                                  float* __restrict__ partials) {
    int blk = blockIdx.x;
    int bg = blk >> 3;
    int part = blk & 7;
    const float4* xp4 = (const float4*)(x + (size_t)bg * (CPG * N) + (size_t)part * (CPG * N / 8));
    float s = 0.f, ss = 0.f;
    for (int i = threadIdx.x; i < 4096; i += 256) {   // 16384 floats per part
        float4 v = xp4[i];
        s  += v.x + v.y + v.z + v.w;
        ss += v.x*v.x + v.y*v.y + v.z*v.z + v.w*v.w;
    }
    __shared__ float rs[256], rss[256];
    rs[threadIdx.x] = s; rss[threadIdx.x] = ss;
    __syncthreads();
    for (int off = 128; off > 0; off >>= 1) {
        if (threadIdx.x < off) {
            rs[threadIdx.x]  += rs[threadIdx.x + off];
            rss[threadIdx.x] += rss[threadIdx.x + off];
        }
        __syncthreads();
    }
    if (threadIdx.x == 0) {
        partials[(bg*8 + part)*2]     = rs[0];
        partials[(bg*8 + part)*2 + 1] = rss[0];
    }
}

// ---------------- K1b: finalize mu/rstd ----------------
__global__ void gn_final(const float* __restrict__ partials, float* __restrict__ stats) {
    int t = threadIdx.x;
    if (t < 32) {
        float s = 0.f, ss = 0.f;
        for (int p = 0; p < 8; p++) {
            s  += partials[(t*8 + p)*2];
            ss += partials[(t*8 + p)*2 + 1];
        }
        const float inv = 1.f / 131072.f;
        float mu = s * inv;
        float var = fmaxf(ss * inv - mu*mu, 0.f);
        stats[t*2]     = mu;
        stats[t*2 + 1] = rsqrtf(var + EPSV);
    }
}

// ---------------- K2: fused groupnorm + QKV GEMM ----------------
// per batch: out[o][n] = sum_c W[o][c]*h[c][n] + bias[o]; stored as [B][N][C] q/k/v
__global__ __launch_bounds__(256) void qkv_gemm(const float* __restrict__ x,
        const float* __restrict__ w, const float* __restrict__ bias,
        const float* __restrict__ gamma, const float* __restrict__ beta,
        const float* __restrict__ stats,
        float* __restrict__ qb, float* __restrict__ kb, float* __restrict__ vb) {
    int b  = blockIdx.z;
    int o0 = blockIdx.y * 64;
    int n0 = blockIdx.x * 64;
    __shared__ float Wt[64][33];
    __shared__ float Ht[32][65];
    int tid = threadIdx.x;
    int tx = tid & 15, ty = tid >> 4;
    float acc[4][4];
    #pragma unroll
    for (int i = 0; i < 4; i++)
        #pragma unroll
        for (int j = 0; j < 4; j++) acc[i][j] = 0.f;

    for (int c0 = 0; c0 < C; c0 += 32) {
        #pragma unroll
        for (int l = 0; l < 8; l++) {               // W tile 64x32
            int idx = tid + l*256;
            int r = idx >> 5, cc = idx & 31;
            Wt[r][cc] = w[(size_t)(o0 + r)*C + c0 + cc];
        }
        #pragma unroll
        for (int l = 0; l < 8; l++) {               // H tile 32x64 (normalized on load)
            int idx = tid + l*256;
            int cc = idx >> 6, nn = idx & 63;
            int c = c0 + cc;
            int g = c >> 5;
            float mu   = stats[(b*G + g)*2];
            float rstd = stats[(b*G + g)*2 + 1];
            float v = x[((size_t)b*C + c)*N + n0 + nn];
            Ht[cc][nn] = (v - mu)*rstd*gamma[c] + beta[c];
        }
        __syncthreads();
        #pragma unroll
        for (int cc = 0; cc < 32; cc++) {
            float a[4], bb[4];
            #pragma unroll
            for (int j = 0; j < 4; j++) a[j]  = Wt[tx*4 + j][cc];   // o dim
            #pragma unroll
            for (int i = 0; i < 4; i++) bb[i] = Ht[cc][ty*4 + i];   // n dim
            #pragma unroll
            for (int i = 0; i < 4; i++)
                #pragma unroll
                for (int j = 0; j < 4; j++) acc[i][j] += a[j]*bb[i];
        }
        __syncthreads();
    }
    // route to q/k/v (o-tile of 64 never straddles a 256 boundary)
    float* dst; int cbase;
    if (o0 < 256)      { dst = qb; cbase = o0; }
    else if (o0 < 512) { dst = kb; cbase = o0 - 256; }
    else               { dst = vb; cbase = o0 - 512; }
    #pragma unroll
    for (int i = 0; i < 4; i++) {
        int n = n0 + ty*4 + i;
        float4 v;
        v.x = acc[i][0] + bias[o0 + tx*4 + 0];
        v.y = acc[i][1] + bias[o0 + tx*4 + 1];
        v.z = acc[i][2] + bias[o0 + tx*4 + 2];
        v.w = acc[i][3] + bias[o0 + tx*4 + 3];
        *(float4*)&dst[((size_t)b*N + n)*C + cbase + tx*4] = v;
    }
}

// ---------------- K3: flash-style attention ----------------
#define QT 32
#define KT 16
#define CP 260   // padded row: 1040B, 16B-aligned, breaks power-of-2 bank stride

__global__ __launch_bounds__(256) void attn_kernel(const float* __restrict__ qb,
        const float* __restrict__ kb, const float* __restrict__ vb,
        float* __restrict__ ob) {
    int b  = blockIdx.y;
    int n0 = blockIdx.x * QT;
    __shared__ float Qs[QT][CP];
    __shared__ float Ks[KT][CP];
    __shared__ float Vs[KT][CP];
    __shared__ float Ps[QT][KT + 1];
    int tid = threadIdx.x;
    int i  = tid >> 3;     // query row 0..31 (8 lanes per row, same wave)
    int t8 = tid & 7;

    const float* qrow = qb + ((size_t)b*N + n0)*C;
    #pragma unroll
    for (int l = 0; l < 8; l++) {                   // load+scale Q: 32x256
        int idx = tid + l*256;
        int r = idx >> 6, c4 = idx & 63;
        float4 v = *(const float4*)&qrow[(size_t)r*C + c4*4];
        v.x *= SCALE; v.y *= SCALE; v.z *= SCALE; v.w *= SCALE;
        *(float4*)&Qs[r][c4*4] = v;
    }

    float4 o4[8];
    #pragma unroll
    for (int q = 0; q < 8; q++) o4[q] = make_float4(0.f, 0.f, 0.f, 0.f);
    float m = -INFINITY, l_sum = 0.f;

    for (int m0 = 0; m0 < N; m0 += KT) {
        __syncthreads();   // everyone done reading previous Ks/Vs
        const float* krow = kb + ((size_t)b*N + m0)*C;
        const float* vrow = vb + ((size_t)b*N + m0)*C;
        #pragma unroll
        for (int l = 0; l < 4; l++) {               // K,V chunk 16x256 each
            int idx = tid + l*256;
            int r = idx >> 6, c4 = idx & 63;
            *(float4*)&Ks[r][c4*4] = *(const float4*)&krow[(size_t)r*C + c4*4];
            *(float4*)&Vs[r][c4*4] = *(const float4*)&vrow[(size_t)r*C + c4*4];
        }
        __syncthreads();

        // S[i][j2], S[i][j2+1]: dot over 256
        int j2 = t8*2;
        float s0 = 0.f, s1 = 0.f;
        #pragma unroll 16
        for (int c4 = 0; c4 < 64; c4++) {
            float4 qv = *(const float4*)&Qs[i][c4*4];
            float4 k0 = *(const float4*)&Ks[j2][c4*4];
            float4 k1 = *(const float4*)&Ks[j2+1][c4*4];
            s0 += qv.x*k0.x + qv.y*k0.y + qv.z*k0.z + qv.w*k0.w;
            s1 += qv.x*k1.x + qv.y*k1.y + qv.z*k1.z + qv.w*k1.w;
        }
        // online softmax over this 16-wide chunk (8-lane group reduce)
        float mx = fmaxf(s0, s1);
        mx = fmaxf(mx, __shfl_xor(mx, 1));
        mx = fmaxf(mx, __shfl_xor(mx, 2));
        mx = fmaxf(mx, __shfl_xor(mx, 4));
        float m_new = fmaxf(m, mx);
        float fac = __expf(m - m_new);      // first iter: exp(-inf)=0
        float p0 = __expf(s0 - m_new);
        float p1 = __expf(s1 - m_new);
        float ls = p0 + p1;
        ls += __shfl_xor(ls, 1);
        ls += __shfl_xor(ls, 2);
        ls += __shfl_xor(ls, 4);
        l_sum = l_sum * fac + ls;
        m = m_new;
        Ps[i][j2] = p0; Ps[i][j2 + 1] = p1;   // same-wave produce/consume, no barrier
        #pragma unroll
        for (int q = 0; q < 8; q++) {
            o4[q].x *= fac; o4[q].y *= fac; o4[q].z *= fac; o4[q].w *= fac;
        }
        // O += P * V   (thread owns c = t8*4 + 32*q .. +3)
        #pragma unroll
        for (int j = 0; j < KT; j++) {
            float p = Ps[i][j];
            #pragma unroll
            for (int q = 0; q < 8; q++) {
                float4 v = *(const float4*)&Vs[j][t8*4 + 32*q];
                o4[q].x += p*v.x; o4[q].y += p*v.y; o4[q].z += p*v.z; o4[q].w += p*v.w;
            }
        }
    }
    float invl = 1.f / l_sum;
    float* orow = ob + ((size_t)b*N + n0 + i)*C;
    #pragma unroll
    for (int q = 0; q < 8; q++) {
        float4 r = o4[q];
        r.x *= invl; r.y *= invl; r.z *= invl; r.w *= invl;
        *(float4*)&orow[t8*4 + 32*q] = r;
    }
}

// ---------------- K4: proj GEMM + residual ----------------
__global__ __launch_bounds__(256) void proj_kernel(const float* __restrict__ ob,
        const float* __restrict__ wp, const float* __restrict__ bp,
        const float* __restrict__ x, float* __restrict__ out) {
    int b   = blockIdx.z;
    int co0 = blockIdx.y * 64;
    int n0  = blockIdx.x * 64;
    __shared__ float Wt[64][33];
    __shared__ float Ot[32][65];
    int tid = threadIdx.x;
    int tx = tid & 15, ty = tid >> 4;
    float acc[4][4];
    #pragma unroll
    for (int i = 0; i < 4; i++)
        #pragma unroll
        for (int j = 0; j < 4; j++) acc[i][j] = 0.f;

    for (int c0 = 0; c0 < C; c0 += 32) {
        #pragma unroll
        for (int l = 0; l < 8; l++) {               // W tile 64x32
            int idx = tid + l*256;
            int r = idx >> 5, cc = idx & 31;
            Wt[r][cc] = wp[(size_t)(co0 + r)*C + c0 + cc];
        }
        #pragma unroll
        for (int l = 0; l < 8; l++) {               // O tile transposed: [cc][n]
            int idx = tid + l*256;
            int r = idx >> 5, cc = idx & 31;        // r = n offset
            Ot[cc][r] = ob[((size_t)b*N + n0 + r)*C + c0 + cc];
        }
        __syncthreads();
        #pragma unroll
        for (int cc = 0; cc < 32; cc++) {
            float a[4], bn[4];
            #pragma unroll
            for (int i = 0; i < 4; i++) a[i]  = Wt[ty*4 + i][cc];   // co dim
            #pragma unroll
            for (int j = 0; j < 4; j++) bn[j] = Ot[cc][tx*4 + j];   // n dim
            #pragma unroll
            for (int i = 0; i < 4; i++)
                #pragma unroll
                for (int j = 0; j < 4; j++) acc[i][j] += a[i]*bn[j];
        }
        __syncthreads();
    }
    #pragma unroll
    for (int i = 0; i < 4; i++) {
        int co = co0 + ty*4 + i;
        size_t base = ((size_t)b*C + co)*N + n0 + tx*4;
        float4 xr = *(const float4*)&x[base];
        float bpv = bp[co];
        float4 r;
        r.x = acc[i][0] + bpv + xr.x;
        r.y = acc[i][1] + bpv + xr.y;
        r.z = acc[i][2] + bpv + xr.z;
        r.w = acc[i][3] + bpv + xr.w;
        *(float4*)&out[base] = r;
    }
}

extern "C" void kernel_launch(void* const* d_in, const int* in_sizes, int n_in,
                              void* d_out, int out_size, void* d_ws, size_t ws_size,
                              hipStream_t stream) {
    const float* x      = (const float*)d_in[0];
    const float* gamma  = (const float*)d_in[1];
    const float* beta   = (const float*)d_in[2];
    const float* w_qkv  = (const float*)d_in[3];
    const float* b_qkv  = (const float*)d_in[4];
    const float* w_proj = (const float*)d_in[5];
    const float* b_proj = (const float*)d_in[6];
    float* out = (float*)d_out;
    float* ws  = (float*)d_ws;

    size_t NB = (size_t)B * N * C;          // 4,194,304 floats per tensor
    float* qb = ws;
    float* kb = ws + NB;
    float* vb = ws + 2*NB;
    float* obuf = ws + 3*NB;
    float* partials = ws + 4*NB;            // 512 floats
    float* stats    = partials + 512;       // 64 floats

    gn_partial<<<dim3(256), dim3(256), 0, stream>>>(x, partials);
    gn_final<<<dim3(1), dim3(64), 0, stream>>>(partials, stats);
    qkv_gemm<<<dim3(64, 12, 4), dim3(256), 0, stream>>>(x, w_qkv, b_qkv, gamma, beta, stats, qb, kb, vb);
    attn_kernel<<<dim3(128, 4), dim3(256), 0, stream>>>(qb, kb, vb, obuf);
    proj_kernel<<<dim3(64, 4, 4), dim3(256), 0, stream>>>(obuf, w_proj, b_proj, x, out);
}

// Round 3
// 354.710 us; speedup vs baseline: 5.8065x; 5.8065x over previous
//
#include <hip/hip_runtime.h>
#include <hip/hip_bf16.h>
#include <math.h>

#define B 4
#define C 256
#define G 8
#define N 4096
#define EPSV 1e-5f
#define SCALE 0.0625f   // 1/sqrt(256)

typedef __attribute__((ext_vector_type(8))) short short8;
typedef __attribute__((ext_vector_type(16))) float f32x16;
typedef unsigned short ushort_t;
typedef unsigned int uint_t;

// ---- bf16 helpers (bit-level, RNE) ----
__device__ __forceinline__ ushort_t f2bf(float f) {
    union { float f; uint_t u; } c; c.f = f;
    uint_t u = c.u;
    uint_t r = (u + 0x7FFFu + ((u >> 16) & 1u)) >> 16;
    return (ushort_t)r;
}
__device__ __forceinline__ float bf2f(ushort_t h) {
    union { uint_t u; float f; } c; c.u = ((uint_t)h) << 16;
    return c.f;
}
__device__ __forceinline__ uint_t pack2(float a, float b) {
    return (uint_t)f2bf(a) | ((uint_t)f2bf(b) << 16);
}
__device__ __forceinline__ uint_t cvtpk_bf16(float lo, float hi) {
    uint_t r;
    asm("v_cvt_pk_bf16_f32 %0, %1, %2" : "=v"(r) : "v"(lo), "v"(hi));
    return r;
}
__device__ __forceinline__ void gl_lds16(const void* g, void* l) {
    __builtin_amdgcn_global_load_lds(
        (const __attribute__((address_space(1))) void*)g,
        (__attribute__((address_space(3))) void*)l, 16, 0, 0);
}

// ---------------- K1a: groupnorm partial sums ----------------
__global__ __launch_bounds__(256) void gn_partial(const float* __restrict__ x,
                                                  float* __restrict__ partials) {
    int blk = blockIdx.x;
    int bg = blk >> 3;
    int part = blk & 7;
    const float4* xp4 = (const float4*)(x + (size_t)bg * (32 * N) + (size_t)part * (32 * N / 8));
    float s = 0.f, ss = 0.f;
    for (int i = threadIdx.x; i < 4096; i += 256) {
        float4 v = xp4[i];
        s  += v.x + v.y + v.z + v.w;
        ss += v.x*v.x + v.y*v.y + v.z*v.z + v.w*v.w;
    }
    __shared__ float rs[256], rss[256];
    rs[threadIdx.x] = s; rss[threadIdx.x] = ss;
    __syncthreads();
    for (int off = 128; off > 0; off >>= 1) {
        if (threadIdx.x < off) {
            rs[threadIdx.x]  += rs[threadIdx.x + off];
            rss[threadIdx.x] += rss[threadIdx.x + off];
        }
        __syncthreads();
    }
    if (threadIdx.x == 0) {
        partials[(bg*8 + part)*2]     = rs[0];
        partials[(bg*8 + part)*2 + 1] = rss[0];
    }
}

// ---------------- K1b: finalize mu/rstd ----------------
__global__ void gn_final(const float* __restrict__ partials, float* __restrict__ stats) {
    int t = threadIdx.x;
    if (t < 32) {
        float s = 0.f, ss = 0.f;
        for (int p = 0; p < 8; p++) {
            s  += partials[(t*8 + p)*2];
            ss += partials[(t*8 + p)*2 + 1];
        }
        const float inv = 1.f / 131072.f;
        float mu = s * inv;
        float var = fmaxf(ss * inv - mu*mu, 0.f);
        stats[t*2]     = mu;
        stats[t*2 + 1] = rsqrtf(var + EPSV);
    }
}

// ---------------- K2: fused groupnorm + QKV GEMM (fp32 compute, bf16 out) ----------------
// q: bf16 [B][N][C] pre-scaled by 1/16; k: bf16 [B][N][C];
// v: bf16 blocked [B][N/32][C][32]  (i.e. V^T tiles, n-block of 32)
__global__ __launch_bounds__(256) void qkv_gemm(const float* __restrict__ x,
        const float* __restrict__ w, const float* __restrict__ bias,
        const float* __restrict__ gamma, const float* __restrict__ beta,
        const float* __restrict__ stats,
        ushort_t* __restrict__ qbf, ushort_t* __restrict__ kbf, ushort_t* __restrict__ vblk) {
    int b  = blockIdx.z;
    int o0 = blockIdx.y * 64;
    int n0 = blockIdx.x * 64;
    __shared__ float Wt[64][33];
    __shared__ float Ht[32][65];
    int tid = threadIdx.x;
    int tx = tid & 15, ty = tid >> 4;
    float acc[4][4];
    #pragma unroll
    for (int i = 0; i < 4; i++)
        #pragma unroll
        for (int j = 0; j < 4; j++) acc[i][j] = 0.f;

    for (int c0 = 0; c0 < C; c0 += 32) {
        #pragma unroll
        for (int l = 0; l < 8; l++) {
            int idx = tid + l*256;
            int r = idx >> 5, cc = idx & 31;
            Wt[r][cc] = w[(size_t)(o0 + r)*C + c0 + cc];
        }
        #pragma unroll
        for (int l = 0; l < 8; l++) {
            int idx = tid + l*256;
            int cc = idx >> 6, nn = idx & 63;
            int c = c0 + cc;
            int g = c >> 5;
            float mu   = stats[(b*G + g)*2];
            float rstd = stats[(b*G + g)*2 + 1];
            float v = x[((size_t)b*C + c)*N + n0 + nn];
            Ht[cc][nn] = (v - mu)*rstd*gamma[c] + beta[c];
        }
        __syncthreads();
        #pragma unroll
        for (int cc = 0; cc < 32; cc++) {
            float a[4], bb[4];
            #pragma unroll
            for (int j = 0; j < 4; j++) a[j]  = Wt[tx*4 + j][cc];
            #pragma unroll
            for (int i = 0; i < 4; i++) bb[i] = Ht[cc][ty*4 + i];
            #pragma unroll
            for (int i = 0; i < 4; i++)
                #pragma unroll
                for (int j = 0; j < 4; j++) acc[i][j] += a[j]*bb[i];
        }
        __syncthreads();
    }
    int ob_ = o0 + tx*4;
    if (o0 < 512) {
        ushort_t* dst = (o0 < 256) ? qbf : kbf;
        int cb = (o0 < 256) ? ob_ : ob_ - 256;
        float sc = (o0 < 256) ? SCALE : 1.0f;
        #pragma unroll
        for (int i = 0; i < 4; i++) {
            int n = n0 + ty*4 + i;
            float v0 = (acc[i][0] + bias[ob_+0]) * sc;
            float v1 = (acc[i][1] + bias[ob_+1]) * sc;
            float v2 = (acc[i][2] + bias[ob_+2]) * sc;
            float v3 = (acc[i][3] + bias[ob_+3]) * sc;
            uint2 pk; pk.x = pack2(v0, v1); pk.y = pack2(v2, v3);
            *(uint2*)(dst + ((size_t)b*N + n)*256 + cb) = pk;
        }
    } else {
        int cb = ob_ - 512;
        int n31 = (ty*4) & 31;
        size_t nb = (size_t)((n0 + ty*4) >> 5);
        #pragma unroll
        for (int j = 0; j < 4; j++) {
            float bj = bias[ob_ + j];
            uint2 pk;
            pk.x = pack2(acc[0][j]+bj, acc[1][j]+bj);
            pk.y = pack2(acc[2][j]+bj, acc[3][j]+bj);
            *(uint2*)(vblk + (size_t)b*1048576 + nb*8192 + (size_t)(cb+j)*32 + n31) = pk;
        }
    }
}

// ---------------- K3: MFMA flash attention ----------------
// grid 256: f = (qt<<3)|(b<<1)|kvh -> XCD (f&7) owns one (batch, kv-half): 2MB KV fits L2.
// Each of 4 waves owns 32 q rows. S^T = K·Q^T (32x32x16 MFMA), O^T = V^T·P^T.
__global__ __launch_bounds__(256, 1) void attn_mfma(const ushort_t* __restrict__ qbf,
        const ushort_t* __restrict__ kbf, const ushort_t* __restrict__ vblk,
        ushort_t* __restrict__ part, float* __restrict__ ml) {
    int f = blockIdx.x;
    int qt  = f >> 3;
    int b   = (f >> 1) & 3;
    int kvh = f & 1;
    int w = threadIdx.x >> 6;
    int l = threadIdx.x & 63;
    int l31 = l & 31, lh = l >> 5;

    __shared__ short Klds[2][8192];   // [gc 0..31][kv 0..31] 16B units, k-major
    __shared__ short Vlds[2][8192];   // [ks 0..3][c 0..255] 16B units, k-major

    int qbase = qt*128 + w*32;
    // Q fragments in registers: lane holds Q[qbase + l31][16s + lh*8 .. +7]
    short8 qf[16];
    {
        const ushort_t* qrow = qbf + ((size_t)(b*N + qbase + l31))*256;
        #pragma unroll
        for (int s = 0; s < 16; s++)
            qf[s] = *(const short8*)(qrow + s*16 + lh*8);
    }

    f32x16 ot[8];
    #pragma unroll
    for (int mc = 0; mc < 8; mc++)
        #pragma unroll
        for (int r = 0; r < 16; r++) ot[mc][r] = 0.f;
    float m = -INFINITY, lsum = 0.f;

    const char* kbase = (const char*)kbf + (size_t)(b*N)*512;
    const char* vbase = (const char*)vblk + (size_t)b*2097152;

    auto stage = [&](int bb, int m0) {
        const char* ks_ = kbase + ((size_t)(m0 + l31))*512;
        #pragma unroll
        for (int q = 0; q < 4; q++)
            gl_lds16(ks_ + (w*8 + q*2 + lh)*16, &Klds[bb][(w*4+q)*512]);
        const char* vs_ = vbase + (size_t)(m0 >> 5)*16384 + w*16;
        #pragma unroll
        for (int q = 0; q < 4; q++)
            gl_lds16(vs_ + (q*64 + l)*64, &Vlds[bb][(w*4+q)*512]);
    };

    int m0base = kvh*2048;
    stage(0, m0base);
    __syncthreads();
    int buf = 0;

    for (int t = 0; t < 64; t++) {
        if (t < 63) stage(buf^1, m0base + (t+1)*32);

        // ---- QK^T: St = K·Q^T, two accumulators to halve dep chain ----
        f32x16 st0, st1;
        #pragma unroll
        for (int r = 0; r < 16; r++) { st0[r] = 0.f; st1[r] = 0.f; }
        const short* kb_ = &Klds[buf][0];
        #pragma unroll
        for (int s = 0; s < 8; s++) {
            short8 ka = *(const short8*)(kb_ + ((size_t)((4*s   + lh)*32 + l31))*8);
            short8 kc = *(const short8*)(kb_ + ((size_t)((4*s+2 + lh)*32 + l31))*8);
            st0 = __builtin_amdgcn_mfma_f32_32x32x16_bf16(ka, qf[2*s],   st0, 0, 0, 0);
            st1 = __builtin_amdgcn_mfma_f32_32x32x16_bf16(kc, qf[2*s+1], st1, 0, 0, 0);
        }

        float sv[16];
        #pragma unroll
        for (int r = 0; r < 16; r++) sv[r] = st0[r] + st1[r];

        // ---- online softmax (lane-local row: i = l31; partner l^32 has other half) ----
        float pmax = sv[0];
        #pragma unroll
        for (int r = 1; r < 16; r++) pmax = fmaxf(pmax, sv[r]);
        pmax = fmaxf(pmax, __shfl_xor(pmax, 32));
        if (!__all(pmax <= m + 8.0f)) {       // defer-max (T13)
            float mn = fmaxf(m, pmax);
            float fac = __expf(m - mn);
            m = mn;
            lsum *= fac;
            #pragma unroll
            for (int mc = 0; mc < 8; mc++)
                #pragma unroll
                for (int r = 0; r < 16; r++) ot[mc][r] *= fac;
        }
        float p[16]; float ls = 0.f;
        #pragma unroll
        for (int r = 0; r < 16; r++) { p[r] = __expf(sv[r] - m); ls += p[r]; }
        ls += __shfl_xor(ls, 32);
        lsum += ls;

        // ---- P -> bf16 B-fragments via cvt_pk + permlane32_swap (T12) ----
        short8 pf0, pf1;
        {
            uint_t x0 = cvtpk_bf16(p[0], p[1]);
            uint_t y0 = cvtpk_bf16(p[4], p[5]);
            uint_t x1 = cvtpk_bf16(p[2], p[3]);
            uint_t y1 = cvtpk_bf16(p[6], p[7]);
            auto r0 = __builtin_amdgcn_permlane32_swap(x0, y0, false, false);
            auto r1 = __builtin_amdgcn_permlane32_swap(x1, y1, false, false);
            union { uint_t u[4]; short8 s8; } u_;
            u_.u[0] = r0[0]; u_.u[1] = r1[0]; u_.u[2] = r0[1]; u_.u[3] = r1[1];
            pf0 = u_.s8;
            uint_t x2 = cvtpk_bf16(p[8],  p[9]);
            uint_t y2 = cvtpk_bf16(p[12], p[13]);
            uint_t x3 = cvtpk_bf16(p[10], p[11]);
            uint_t y3 = cvtpk_bf16(p[14], p[15]);
            auto r2 = __builtin_amdgcn_permlane32_swap(x2, y2, false, false);
            auto r3 = __builtin_amdgcn_permlane32_swap(x3, y3, false, false);
            union { uint_t u[4]; short8 s8; } u2_;
            u2_.u[0] = r2[0]; u2_.u[1] = r3[0]; u2_.u[2] = r2[1]; u2_.u[3] = r3[1];
            pf1 = u2_.s8;
        }

        // ---- PV: Ot[mc] += Vt·P^T ----
        const short* vb_ = &Vlds[buf][0];
        #pragma unroll
        for (int mc = 0; mc < 8; mc++) {
            short8 v0 = *(const short8*)(vb_ + ((size_t)((lh)*256   + mc*32 + l31))*8);
            short8 v1 = *(const short8*)(vb_ + ((size_t)((2+lh)*256 + mc*32 + l31))*8);
            ot[mc] = __builtin_amdgcn_mfma_f32_32x32x16_bf16(v0, pf0, ot[mc], 0, 0, 0);
            ot[mc] = __builtin_amdgcn_mfma_f32_32x32x16_bf16(v1, pf1, ot[mc], 0, 0, 0);
        }

        __syncthreads();
        buf ^= 1;
    }

    // ---- write normalized partial (bf16) + (m, lsum) ----
    float invl = 1.f / lsum;
    ushort_t* pbase = part + (size_t)kvh*4194304 + ((size_t)(b*N + qbase + l31))*256;
    #pragma unroll
    for (int mc = 0; mc < 8; mc++)
        #pragma unroll
        for (int rp = 0; rp < 8; rp++) {
            int r0 = rp*2;
            uint_t wd = cvtpk_bf16(ot[mc][r0]*invl, ot[mc][r0+1]*invl);
            int c0 = (r0 & 3) + 8*(r0 >> 2) + 4*lh + 32*mc;
            *(uint_t*)(pbase + c0) = wd;
        }
    if (l < 32) {
        size_t row = (size_t)kvh*16384 + b*4096 + qbase + l;
        ml[row*2]     = m;
        ml[row*2 + 1] = lsum;
    }
}

// ---------------- K3b: merge kv-split halves ----------------
__global__ __launch_bounds__(256) void attn_merge(const ushort_t* __restrict__ part,
        const float* __restrict__ ml, ushort_t* __restrict__ ob) {
    int t = blockIdx.x*256 + threadIdx.x;
    int row = t >> 5;
    int c8 = (t & 31) * 8;
    float m0 = ml[(size_t)row*2],           l0 = ml[(size_t)row*2 + 1];
    float m1 = ml[(size_t)(16384 + row)*2], l1 = ml[(size_t)(16384 + row)*2 + 1];
    float M = fmaxf(m0, m1);
    float w0 = __expf(m0 - M) * l0, w1 = __expf(m1 - M) * l1;
    float inv = 1.f / (w0 + w1);
    w0 *= inv; w1 *= inv;
    const ushort_t* p0 = part + (size_t)row*256 + c8;
    const ushort_t* p1 = p0 + 4194304;
    ushort_t o[8];
    #pragma unroll
    for (int e = 0; e < 8; e++) {
        float v = w0*bf2f(p0[e]) + w1*bf2f(p1[e]);
        o[e] = f2bf(v);
    }
    uint4 pk;
    pk.x = (uint_t)o[0] | ((uint_t)o[1]<<16);
    pk.y = (uint_t)o[2] | ((uint_t)o[3]<<16);
    pk.z = (uint_t)o[4] | ((uint_t)o[5]<<16);
    pk.w = (uint_t)o[6] | ((uint_t)o[7]<<16);
    *(uint4*)(ob + (size_t)row*256 + c8) = pk;
}

// ---------------- K4: proj GEMM + residual (bf16 in, fp32 out) ----------------
__global__ __launch_bounds__(256) void proj_kernel(const ushort_t* __restrict__ ob,
        const float* __restrict__ wp, const float* __restrict__ bp,
        const float* __restrict__ x, float* __restrict__ out) {
    int b   = blockIdx.z;
    int co0 = blockIdx.y * 64;
    int n0  = blockIdx.x * 64;
    __shared__ float Wt[64][33];
    __shared__ float Ot[32][65];
    int tid = threadIdx.x;
    int tx = tid & 15, ty = tid >> 4;
    float acc[4][4];
    #pragma unroll
    for (int i = 0; i < 4; i++)
        #pragma unroll
        for (int j = 0; j < 4; j++) acc[i][j] = 0.f;

    for (int c0 = 0; c0 < C; c0 += 32) {
        #pragma unroll
        for (int l = 0; l < 8; l++) {
            int idx = tid + l*256;
            int r = idx >> 5, cc = idx & 31;
            Wt[r][cc] = wp[(size_t)(co0 + r)*C + c0 + cc];
        }
        #pragma unroll
        for (int l = 0; l < 8; l++) {
            int idx = tid + l*256;
            int r = idx >> 5, cc = idx & 31;
            Ot[cc][r] = bf2f(ob[((size_t)b*N + n0 + r)*256 + c0 + cc]);
        }
        __syncthreads();
        #pragma unroll
        for (int cc = 0; cc < 32; cc++) {
            float a[4], bn[4];
            #pragma unroll
            for (int i = 0; i < 4; i++) a[i]  = Wt[ty*4 + i][cc];
            #pragma unroll
            for (int j = 0; j < 4; j++) bn[j] = Ot[cc][tx*4 + j];
            #pragma unroll
            for (int i = 0; i < 4; i++)
                #pragma unroll
                for (int j = 0; j < 4; j++) acc[i][j] += a[i]*bn[j];
        }
        __syncthreads();
    }
    #pragma unroll
    for (int i = 0; i < 4; i++) {
        int co = co0 + ty*4 + i;
        size_t base = ((size_t)b*C + co)*N + n0 + tx*4;
        float4 xr = *(const float4*)&x[base];
        float bpv = bp[co];
        float4 r;
        r.x = acc[i][0] + bpv + xr.x;
        r.y = acc[i][1] + bpv + xr.y;
        r.z = acc[i][2] + bpv + xr.z;
        r.w = acc[i][3] + bpv + xr.w;
        *(float4*)&out[base] = r;
    }
}

extern "C" void kernel_launch(void* const* d_in, const int* in_sizes, int n_in,
                              void* d_out, int out_size, void* d_ws, size_t ws_size,
                              hipStream_t stream) {
    const float* x      = (const float*)d_in[0];
    const float* gamma  = (const float*)d_in[1];
    const float* beta   = (const float*)d_in[2];
    const float* w_qkv  = (const float*)d_in[3];
    const float* b_qkv  = (const float*)d_in[4];
    const float* w_proj = (const float*)d_in[5];
    const float* b_proj = (const float*)d_in[6];
    float* out = (float*)d_out;
    char* wsb  = (char*)d_ws;

    ushort_t* qbf  = (ushort_t*)(wsb);               // 8 MB
    ushort_t* kbf  = (ushort_t*)(wsb + 8388608);     // 8 MB
    ushort_t* vblk = (ushort_t*)(wsb + 16777216);    // 8 MB
    ushort_t* part = (ushort_t*)(wsb + 25165824);    // 16 MB (2 halves)
    float*    ml   = (float*)  (wsb + 41943040);     // 256 KB
    ushort_t* ob   = (ushort_t*)(wsb + 42205184);    // 8 MB
    float* partials = (float*) (wsb + 50593792);
    float* stats    = partials + 512;

    gn_partial<<<dim3(256), dim3(256), 0, stream>>>(x, partials);
    gn_final<<<dim3(1), dim3(64), 0, stream>>>(partials, stats);
    qkv_gemm<<<dim3(64, 12, 4), dim3(256), 0, stream>>>(x, w_qkv, b_qkv, gamma, beta, stats, qbf, kbf, vblk);
    attn_mfma<<<dim3(256), dim3(256), 0, stream>>>(qbf, kbf, vblk, part, ml);
    attn_merge<<<dim3(2048), dim3(256), 0, stream>>>(part, ml, ob);
    proj_kernel<<<dim3(64, 4, 4), dim3(256), 0, stream>>>(ob, w_proj, b_proj, x, out);
}

// Round 4
// 192.163 us; speedup vs baseline: 10.7182x; 1.8459x over previous
//
#include <hip/hip_runtime.h>
#include <hip/hip_bf16.h>
#include <math.h>

#define B 4
#define C 256
#define G 8
#define N 4096
#define EPSV 1e-5f
#define SCALE 0.0625f   // 1/sqrt(256)

typedef __attribute__((ext_vector_type(8))) short short8;
typedef __attribute__((ext_vector_type(16))) float f32x16;
typedef unsigned short ushort_t;
typedef unsigned int uint_t;

// ---- bf16 helpers (bit-level, RNE) ----
__device__ __forceinline__ ushort_t f2bf(float f) {
    union { float f; uint_t u; } c; c.f = f;
    uint_t u = c.u;
    uint_t r = (u + 0x7FFFu + ((u >> 16) & 1u)) >> 16;
    return (ushort_t)r;
}
__device__ __forceinline__ float bf2f(ushort_t h) {
    union { uint_t u; float f; } c; c.u = ((uint_t)h) << 16;
    return c.f;
}
__device__ __forceinline__ uint_t pack2(float a, float b) {
    return (uint_t)f2bf(a) | ((uint_t)f2bf(b) << 16);
}
__device__ __forceinline__ uint_t cvtpk_bf16(float lo, float hi) {
    uint_t r;
    asm("v_cvt_pk_bf16_f32 %0, %1, %2" : "=v"(r) : "v"(lo), "v"(hi));
    return r;
}
__device__ __forceinline__ void gl_lds16(const void* g, void* l) {
    __builtin_amdgcn_global_load_lds(
        (const __attribute__((address_space(1))) void*)g,
        (__attribute__((address_space(3))) void*)l, 16, 0, 0);
}

// ---------------- K0: weights fp32 -> bf16 (w_qkv ++ w_proj) ----------------
__global__ __launch_bounds__(256) void wconv(const float* __restrict__ wq,
        const float* __restrict__ wp, ushort_t* __restrict__ wbf) {
    int idx = blockIdx.x*256 + threadIdx.x;
    #pragma unroll
    for (int p = 0; p < 4; p++) {
        int id = idx + p*16384;   // float4 index, total 65536 (= (768+256)*256/4)
        float4 v = (id < 49152) ? ((const float4*)wq)[id] : ((const float4*)wp)[id - 49152];
        uint2 pk; pk.x = pack2(v.x, v.y); pk.y = pack2(v.z, v.w);
        *(uint2*)&wbf[(size_t)id*4] = pk;
    }
}

// ---------------- K1a: groupnorm partial sums ----------------
__global__ __launch_bounds__(256) void gn_partial(const float* __restrict__ x,
                                                  float* __restrict__ partials) {
    int blk = blockIdx.x;
    int bg = blk >> 3;
    int part = blk & 7;
    const float4* xp4 = (const float4*)(x + (size_t)bg * (32 * N) + (size_t)part * (32 * N / 8));
    float s = 0.f, ss = 0.f;
    for (int i = threadIdx.x; i < 4096; i += 256) {
        float4 v = xp4[i];
        s  += v.x + v.y + v.z + v.w;
        ss += v.x*v.x + v.y*v.y + v.z*v.z + v.w*v.w;
    }
    __shared__ float rs[256], rss[256];
    rs[threadIdx.x] = s; rss[threadIdx.x] = ss;
    __syncthreads();
    for (int off = 128; off > 0; off >>= 1) {
        if (threadIdx.x < off) {
            rs[threadIdx.x]  += rs[threadIdx.x + off];
            rss[threadIdx.x] += rss[threadIdx.x + off];
        }
        __syncthreads();
    }
    if (threadIdx.x == 0) {
        partials[(bg*8 + part)*2]     = rs[0];
        partials[(bg*8 + part)*2 + 1] = rss[0];
    }
}

// ---------------- K1b: finalize mu/rstd ----------------
__global__ void gn_final(const float* __restrict__ partials, float* __restrict__ stats) {
    int t = threadIdx.x;
    if (t < 32) {
        float s = 0.f, ss = 0.f;
        for (int p = 0; p < 8; p++) {
            s  += partials[(t*8 + p)*2];
            ss += partials[(t*8 + p)*2 + 1];
        }
        const float inv = 1.f / 131072.f;
        float mu = s * inv;
        float var = fmaxf(ss * inv - mu*mu, 0.f);
        stats[t*2]     = mu;
        stats[t*2 + 1] = rsqrtf(var + EPSV);
    }
}

// ---------------- K1c: normalize + transpose -> hbf[b][n][c] bf16 ----------------
// Each thread handles a 4c x 4n register sub-tile; no LDS.
__global__ __launch_bounds__(256) void norm_bf16(const float* __restrict__ x,
        const float* __restrict__ gamma, const float* __restrict__ beta,
        const float* __restrict__ stats, ushort_t* __restrict__ hbf) {
    int b = blockIdx.z, c0 = blockIdx.y*64, n0 = blockIdx.x*64;
    int t = threadIdx.x;
    int cq = t >> 4, nq = t & 15;
    ushort_t hv[4][4];
    #pragma unroll
    for (int i = 0; i < 4; i++) {
        int c = c0 + cq*4 + i;
        int g = c >> 5;
        float mu = stats[(b*G+g)*2], rs = stats[(b*G+g)*2+1];
        float ga = gamma[c]*rs;
        float be = beta[c] - mu*ga;
        float4 v = *(const float4*)&x[((size_t)(b*C + c))*N + n0 + nq*4];
        hv[i][0] = f2bf(v.x*ga + be);
        hv[i][1] = f2bf(v.y*ga + be);
        hv[i][2] = f2bf(v.z*ga + be);
        hv[i][3] = f2bf(v.w*ga + be);
    }
    #pragma unroll
    for (int j = 0; j < 4; j++) {
        uint2 pk;
        pk.x = (uint_t)hv[0][j] | ((uint_t)hv[1][j]<<16);
        pk.y = (uint_t)hv[2][j] | ((uint_t)hv[3][j]<<16);
        *(uint2*)&hbf[((size_t)(b*N + n0 + nq*4 + j))*256 + c0 + cq*4] = pk;
    }
}

// ---------------- K2: QKV GEMM, bf16 MFMA ----------------
// out[o][n] = sum_c wbf[o][c]*hbf[n][c].  BM=128(o) BN=128(n) BK=64, 4 waves.
// LDS chunked layout: unit16B[chunk=k/8][row], conflict-free ds_read_b128.
__global__ __launch_bounds__(256) void qkv_mfma(const ushort_t* __restrict__ hbf,
        const ushort_t* __restrict__ wbf, const float* __restrict__ bias,
        ushort_t* __restrict__ qbf, ushort_t* __restrict__ kbf, ushort_t* __restrict__ vblk) {
    int b = blockIdx.z, o0 = blockIdx.y*128, n0 = blockIdx.x*128;
    int tid = threadIdx.x;
    int w = tid>>6, l = tid&63, l31 = l&31, lh = l>>5;
    __shared__ short Ws[2][8192];
    __shared__ short Hs[2][8192];

    const ushort_t* wb = wbf + (size_t)o0*256;
    const ushort_t* hb = hbf + ((size_t)b*N + n0)*256;

    auto stage = [&](int bb, int c0) {
        #pragma unroll
        for (int q = 0; q < 4; q++) {
            int u0 = (q*4 + w)*64;           // wave-uniform dest unit base
            int u  = u0 + l;
            int row = u & 127, ch = u >> 7;
            gl_lds16(wb + (size_t)row*256 + c0 + ch*8, &Ws[bb][u0*8]);
            gl_lds16(hb + (size_t)row*256 + c0 + ch*8, &Hs[bb][u0*8]);
        }
    };

    f32x16 acc[4];
    #pragma unroll
    for (int nf = 0; nf < 4; nf++)
        #pragma unroll
        for (int r = 0; r < 16; r++) acc[nf][r] = 0.f;

    stage(0, 0);
    __syncthreads();
    for (int t = 0; t < 4; t++) {
        int bb = t & 1;
        if (t < 3) stage(bb^1, (t+1)*64);
        short8 af[4];
        #pragma unroll
        for (int s = 0; s < 4; s++)
            af[s] = *(const short8*)&Ws[bb][((2*s+lh)*128 + w*32 + l31)*8];
        #pragma unroll
        for (int nf = 0; nf < 4; nf++) {
            #pragma unroll
            for (int s = 0; s < 4; s++) {
                short8 hf = *(const short8*)&Hs[bb][((2*s+lh)*128 + nf*32 + l31)*8];
                acc[nf] = __builtin_amdgcn_mfma_f32_32x32x16_bf16(af[s], hf, acc[nf], 0, 0, 0);
            }
        }
        __syncthreads();   // compiler drains vmcnt+lgkmcnt before s_barrier
    }

    int ow = o0 + w*32;
    float bv[16];
    #pragma unroll
    for (int r = 0; r < 16; r++) bv[r] = bias[ow + (r&3) + 8*(r>>2) + 4*lh];

    if (ow < 512) {
        ushort_t* dst = (ow < 256) ? qbf : kbf;
        int cb = ow & 255;
        float sc = (ow < 256) ? SCALE : 1.0f;
        #pragma unroll
        for (int nf = 0; nf < 4; nf++) {
            int n = n0 + nf*32 + l31;
            ushort_t* row = dst + ((size_t)(b*N + n))*256 + cb;
            #pragma unroll
            for (int rp = 0; rp < 8; rp++) {
                int r0 = rp*2;
                int cl = (r0&3) + 8*(r0>>2) + 4*lh;
                uint_t wd = cvtpk_bf16((acc[nf][r0]+bv[r0])*sc, (acc[nf][r0+1]+bv[r0+1])*sc);
                *(uint_t*)(row + cl) = wd;
            }
        }
    } else {
        int cb = ow - 512;
        #pragma unroll
        for (int nf = 0; nf < 4; nf++) {
            int n = n0 + nf*32 + l31;
            ushort_t* base = vblk + (size_t)b*1048576 + (size_t)(n>>5)*8192 + (size_t)cb*32 + (n&31);
            #pragma unroll
            for (int r = 0; r < 16; r++) {
                int cl = (r&3) + 8*(r>>2) + 4*lh;
                base[(size_t)cl*32] = f2bf(acc[nf][r] + bv[r]);
            }
        }
    }
}

// ---------------- K3: MFMA flash attention (unchanged, verified) ----------------
__global__ __launch_bounds__(256, 1) void attn_mfma(const ushort_t* __restrict__ qbf,
        const ushort_t* __restrict__ kbf, const ushort_t* __restrict__ vblk,
        ushort_t* __restrict__ part, float* __restrict__ ml) {
    int f = blockIdx.x;
    int qt  = f >> 3;
    int b   = (f >> 1) & 3;
    int kvh = f & 1;
    int w = threadIdx.x >> 6;
    int l = threadIdx.x & 63;
    int l31 = l & 31, lh = l >> 5;

    __shared__ short Klds[2][8192];
    __shared__ short Vlds[2][8192];

    int qbase = qt*128 + w*32;
    short8 qf[16];
    {
        const ushort_t* qrow = qbf + ((size_t)(b*N + qbase + l31))*256;
        #pragma unroll
        for (int s = 0; s < 16; s++)
            qf[s] = *(const short8*)(qrow + s*16 + lh*8);
    }

    f32x16 ot[8];
    #pragma unroll
    for (int mc = 0; mc < 8; mc++)
        #pragma unroll
        for (int r = 0; r < 16; r++) ot[mc][r] = 0.f;
    float m = -INFINITY, lsum = 0.f;

    const char* kbase = (const char*)kbf + (size_t)(b*N)*512;
    const char* vbase = (const char*)vblk + (size_t)b*2097152;

    auto stage = [&](int bb, int m0) {
        const char* ks_ = kbase + ((size_t)(m0 + l31))*512;
        #pragma unroll
        for (int q = 0; q < 4; q++)
            gl_lds16(ks_ + (w*8 + q*2 + lh)*16, &Klds[bb][(w*4+q)*512]);
        const char* vs_ = vbase + (size_t)(m0 >> 5)*16384 + w*16;
        #pragma unroll
        for (int q = 0; q < 4; q++)
            gl_lds16(vs_ + (q*64 + l)*64, &Vlds[bb][(w*4+q)*512]);
    };

    int m0base = kvh*2048;
    stage(0, m0base);
    __syncthreads();
    int buf = 0;

    for (int t = 0; t < 64; t++) {
        if (t < 63) stage(buf^1, m0base + (t+1)*32);

        f32x16 st0, st1;
        #pragma unroll
        for (int r = 0; r < 16; r++) { st0[r] = 0.f; st1[r] = 0.f; }
        const short* kb_ = &Klds[buf][0];
        #pragma unroll
        for (int s = 0; s < 8; s++) {
            short8 ka = *(const short8*)(kb_ + ((size_t)((4*s   + lh)*32 + l31))*8);
            short8 kc = *(const short8*)(kb_ + ((size_t)((4*s+2 + lh)*32 + l31))*8);
            st0 = __builtin_amdgcn_mfma_f32_32x32x16_bf16(ka, qf[2*s],   st0, 0, 0, 0);
            st1 = __builtin_amdgcn_mfma_f32_32x32x16_bf16(kc, qf[2*s+1], st1, 0, 0, 0);
        }

        float sv[16];
        #pragma unroll
        for (int r = 0; r < 16; r++) sv[r] = st0[r] + st1[r];

        float pmax = sv[0];
        #pragma unroll
        for (int r = 1; r < 16; r++) pmax = fmaxf(pmax, sv[r]);
        pmax = fmaxf(pmax, __shfl_xor(pmax, 32));
        if (!__all(pmax <= m + 8.0f)) {
            float mn = fmaxf(m, pmax);
            float fac = __expf(m - mn);
            m = mn;
            lsum *= fac;
            #pragma unroll
            for (int mc = 0; mc < 8; mc++)
                #pragma unroll
                for (int r = 0; r < 16; r++) ot[mc][r] *= fac;
        }
        float p[16]; float ls = 0.f;
        #pragma unroll
        for (int r = 0; r < 16; r++) { p[r] = __expf(sv[r] - m); ls += p[r]; }
        ls += __shfl_xor(ls, 32);
        lsum += ls;

        short8 pf0, pf1;
        {
            uint_t x0 = cvtpk_bf16(p[0], p[1]);
            uint_t y0 = cvtpk_bf16(p[4], p[5]);
            uint_t x1 = cvtpk_bf16(p[2], p[3]);
            uint_t y1 = cvtpk_bf16(p[6], p[7]);
            auto r0 = __builtin_amdgcn_permlane32_swap(x0, y0, false, false);
            auto r1 = __builtin_amdgcn_permlane32_swap(x1, y1, false, false);
            union { uint_t u[4]; short8 s8; } u_;
            u_.u[0] = r0[0]; u_.u[1] = r1[0]; u_.u[2] = r0[1]; u_.u[3] = r1[1];
            pf0 = u_.s8;
            uint_t x2 = cvtpk_bf16(p[8],  p[9]);
            uint_t y2 = cvtpk_bf16(p[12], p[13]);
            uint_t x3 = cvtpk_bf16(p[10], p[11]);
            uint_t y3 = cvtpk_bf16(p[14], p[15]);
            auto r2 = __builtin_amdgcn_permlane32_swap(x2, y2, false, false);
            auto r3 = __builtin_amdgcn_permlane32_swap(x3, y3, false, false);
            union { uint_t u[4]; short8 s8; } u2_;
            u2_.u[0] = r2[0]; u2_.u[1] = r3[0]; u2_.u[2] = r2[1]; u2_.u[3] = r3[1];
            pf1 = u2_.s8;
        }

        const short* vb_ = &Vlds[buf][0];
        #pragma unroll
        for (int mc = 0; mc < 8; mc++) {
            short8 v0 = *(const short8*)(vb_ + ((size_t)((lh)*256   + mc*32 + l31))*8);
            short8 v1 = *(const short8*)(vb_ + ((size_t)((2+lh)*256 + mc*32 + l31))*8);
            ot[mc] = __builtin_amdgcn_mfma_f32_32x32x16_bf16(v0, pf0, ot[mc], 0, 0, 0);
            ot[mc] = __builtin_amdgcn_mfma_f32_32x32x16_bf16(v1, pf1, ot[mc], 0, 0, 0);
        }

        __syncthreads();
        buf ^= 1;
    }

    float invl = 1.f / lsum;
    ushort_t* pbase = part + (size_t)kvh*4194304 + ((size_t)(b*N + qbase + l31))*256;
    #pragma unroll
    for (int mc = 0; mc < 8; mc++)
        #pragma unroll
        for (int rp = 0; rp < 8; rp++) {
            int r0 = rp*2;
            uint_t wd = cvtpk_bf16(ot[mc][r0]*invl, ot[mc][r0+1]*invl);
            int c0 = (r0 & 3) + 8*(r0 >> 2) + 4*lh + 32*mc;
            *(uint_t*)(pbase + c0) = wd;
        }
    if (l < 32) {
        size_t row = (size_t)kvh*16384 + b*4096 + qbase + l;
        ml[row*2]     = m;
        ml[row*2 + 1] = lsum;
    }
}

// ---------------- K3b: merge kv-split halves ----------------
__global__ __launch_bounds__(256) void attn_merge(const ushort_t* __restrict__ part,
        const float* __restrict__ ml, ushort_t* __restrict__ ob) {
    int t = blockIdx.x*256 + threadIdx.x;
    int row = t >> 5;
    int c8 = (t & 31) * 8;
    float m0 = ml[(size_t)row*2],           l0 = ml[(size_t)row*2 + 1];
    float m1 = ml[(size_t)(16384 + row)*2], l1 = ml[(size_t)(16384 + row)*2 + 1];
    float M = fmaxf(m0, m1);
    float w0 = __expf(m0 - M) * l0, w1 = __expf(m1 - M) * l1;
    float inv = 1.f / (w0 + w1);
    w0 *= inv; w1 *= inv;
    const ushort_t* p0 = part + (size_t)row*256 + c8;
    const ushort_t* p1 = p0 + 4194304;
    ushort_t o[8];
    #pragma unroll
    for (int e = 0; e < 8; e++) {
        float v = w0*bf2f(p0[e]) + w1*bf2f(p1[e]);
        o[e] = f2bf(v);
    }
    uint4 pk;
    pk.x = (uint_t)o[0] | ((uint_t)o[1]<<16);
    pk.y = (uint_t)o[2] | ((uint_t)o[3]<<16);
    pk.z = (uint_t)o[4] | ((uint_t)o[5]<<16);
    pk.w = (uint_t)o[6] | ((uint_t)o[7]<<16);
    *(uint4*)(ob + (size_t)row*256 + c8) = pk;
}

// ---------------- K4: proj GEMM bf16 MFMA + bias + residual ----------------
__global__ __launch_bounds__(256) void proj_mfma(const ushort_t* __restrict__ obf,
        const ushort_t* __restrict__ wpbf, const float* __restrict__ bp,
        const float* __restrict__ x, float* __restrict__ out) {
    int b = blockIdx.z, o0 = blockIdx.y*128, n0 = blockIdx.x*128;
    int tid = threadIdx.x;
    int w = tid>>6, l = tid&63, l31 = l&31, lh = l>>5;
    __shared__ short Ws[2][8192];
    __shared__ short Hs[2][8192];

    const ushort_t* wb = wpbf + (size_t)o0*256;
    const ushort_t* hb = obf + ((size_t)b*N + n0)*256;

    auto stage = [&](int bb, int c0) {
        #pragma unroll
        for (int q = 0; q < 4; q++) {
            int u0 = (q*4 + w)*64;
            int u  = u0 + l;
            int row = u & 127, ch = u >> 7;
            gl_lds16(wb + (size_t)row*256 + c0 + ch*8, &Ws[bb][u0*8]);
            gl_lds16(hb + (size_t)row*256 + c0 + ch*8, &Hs[bb][u0*8]);
        }
    };

    f32x16 acc[4];
    #pragma unroll
    for (int nf = 0; nf < 4; nf++)
        #pragma unroll
        for (int r = 0; r < 16; r++) acc[nf][r] = 0.f;

    stage(0, 0);
    __syncthreads();
    for (int t = 0; t < 4; t++) {
        int bb = t & 1;
        if (t < 3) stage(bb^1, (t+1)*64);
        short8 af[4];
        #pragma unroll
        for (int s = 0; s < 4; s++)
            af[s] = *(const short8*)&Ws[bb][((2*s+lh)*128 + w*32 + l31)*8];
        #pragma unroll
        for (int nf = 0; nf < 4; nf++) {
            #pragma unroll
            for (int s = 0; s < 4; s++) {
                short8 hf = *(const short8*)&Hs[bb][((2*s+lh)*128 + nf*32 + l31)*8];
                acc[nf] = __builtin_amdgcn_mfma_f32_32x32x16_bf16(af[s], hf, acc[nf], 0, 0, 0);
            }
        }
        __syncthreads();
    }

    int cw = o0 + w*32;
    float bv[16];
    #pragma unroll
    for (int r = 0; r < 16; r++) bv[r] = bp[cw + (r&3) + 8*(r>>2) + 4*lh];

    #pragma unroll
    for (int nf = 0; nf < 4; nf++) {
        int n = n0 + nf*32 + l31;
        #pragma unroll
        for (int r = 0; r < 16; r++) {
            int cl = (r&3) + 8*(r>>2) + 4*lh;
            size_t a = ((size_t)b*C + cw + cl)*N + n;
            out[a] = acc[nf][r] + bv[r] + x[a];
        }
    }
}

extern "C" void kernel_launch(void* const* d_in, const int* in_sizes, int n_in,
                              void* d_out, int out_size, void* d_ws, size_t ws_size,
                              hipStream_t stream) {
    const float* x      = (const float*)d_in[0];
    const float* gamma  = (const float*)d_in[1];
    const float* beta   = (const float*)d_in[2];
    const float* w_qkv  = (const float*)d_in[3];
    const float* b_qkv  = (const float*)d_in[4];
    const float* w_proj = (const float*)d_in[5];
    const float* b_proj = (const float*)d_in[6];
    float* out = (float*)d_out;
    char* wsb  = (char*)d_ws;

    ushort_t* qbf  = (ushort_t*)(wsb);               // 8 MB
    ushort_t* kbf  = (ushort_t*)(wsb + 8388608);     // 8 MB
    ushort_t* vblk = (ushort_t*)(wsb + 16777216);    // 8 MB
    ushort_t* part = (ushort_t*)(wsb + 25165824);    // 16 MB (2 halves)
    ushort_t* hbf  = (ushort_t*)(wsb + 25165824);    // 8 MB, aliases part (dead until attn)
    float*    ml   = (float*)  (wsb + 41943040);     // 256 KB
    ushort_t* ob   = (ushort_t*)(wsb + 42205184);    // 8 MB
    float* partials = (float*) (wsb + 50593792);     // 2 KB
    float* stats    = partials + 512;                // 256 B
    ushort_t* wbf  = (ushort_t*)(wsb + 50597888);    // 512 KB (w_qkv ++ w_proj, bf16)

    wconv<<<dim3(64), dim3(256), 0, stream>>>(w_qkv, w_proj, wbf);
    gn_partial<<<dim3(256), dim3(256), 0, stream>>>(x, partials);
    gn_final<<<dim3(1), dim3(64), 0, stream>>>(partials, stats);
    norm_bf16<<<dim3(64, 4, 4), dim3(256), 0, stream>>>(x, gamma, beta, stats, hbf);
    qkv_mfma<<<dim3(32, 6, 4), dim3(256), 0, stream>>>(hbf, wbf, b_qkv, qbf, kbf, vblk);
    attn_mfma<<<dim3(256), dim3(256), 0, stream>>>(qbf, kbf, vblk, part, ml);
    attn_merge<<<dim3(2048), dim3(256), 0, stream>>>(part, ml, ob);
    proj_mfma<<<dim3(32, 2, 4), dim3(256), 0, stream>>>(ob, wbf + 196608, b_proj, x, out);
}